// Round 1
// baseline (209.912 us; speedup 1.0000x reference)
//
#include <hip/hip_runtime.h>
#include <hip/hip_bf16.h>
#include <stdint.h>

#define M_DIM 8192
#define K_DIM 4096
#define N_DIM 4096

#define BM 128
#define BN 128
#define BK 128

typedef int i32x4 __attribute__((ext_vector_type(4)));

// ---------------------------------------------------------------------------
// Kernel 1: per-tensor activation quantization f32 -> i8
// x_q = clip(round(x / s) + off, -128, 127)
// Each thread: 16 floats -> 16 bytes. Exact IEEE division to match jnp.
// ---------------------------------------------------------------------------
__global__ __launch_bounds__(256) void quant_x_kernel(
    const float* __restrict__ x, const float* __restrict__ scale_p,
    const int* __restrict__ off_p, int8_t* __restrict__ xq)
{
    const float s = scale_p[0];
    const float off = (float)off_p[0];
    long base = ((long)blockIdx.x * 256 + threadIdx.x) * 16;
    const float4* xin = (const float4*)(x + base);
    float v[16];
    *(float4*)(v + 0)  = xin[0];
    *(float4*)(v + 4)  = xin[1];
    *(float4*)(v + 8)  = xin[2];
    *(float4*)(v + 12) = xin[3];
    uint32_t pk[4];
#pragma unroll
    for (int g = 0; g < 4; ++g) {
        uint32_t p = 0;
#pragma unroll
        for (int j = 0; j < 4; ++j) {
            float q = rintf(v[g * 4 + j] / s) + off;
            q = fminf(fmaxf(q, -128.0f), 127.0f);
            int qi = (int)q;
            p |= ((uint32_t)(qi & 0xff)) << (8 * j);
        }
        pk[g] = p;
    }
    uint4 o; o.x = pk[0]; o.y = pk[1]; o.z = pk[2]; o.w = pk[3];
    *(uint4*)(xq + base) = o;
}

// ---------------------------------------------------------------------------
// Kernel 2: weight pack + permutation fold.
// Bp[j, k] = (int8) weight[index[j], k];  dsp[j] = deq[index[j]]; qbp[j] = qb[index[j]]
// One block per output row j; 256 threads x 16 elems = 4096 = K.
// ---------------------------------------------------------------------------
__global__ __launch_bounds__(256) void pack_w_kernel(
    const int* __restrict__ w, const int* __restrict__ index,
    const float* __restrict__ deq, const int* __restrict__ qb,
    int8_t* __restrict__ bp, float* __restrict__ dsp, int* __restrict__ qbp)
{
    int j = blockIdx.x;
    int t = threadIdx.x;
    int src = index[j];
    const int4* wrow = (const int4*)(w + (long)src * K_DIM);
    uint32_t pk[4];
#pragma unroll
    for (int g = 0; g < 4; ++g) {
        int4 c = wrow[t * 4 + g];
        pk[g] = ((uint32_t)(c.x & 0xff)) | (((uint32_t)(c.y & 0xff)) << 8) |
                (((uint32_t)(c.z & 0xff)) << 16) | (((uint32_t)(c.w & 0xff)) << 24);
    }
    uint4 o; o.x = pk[0]; o.y = pk[1]; o.z = pk[2]; o.w = pk[3];
    *(uint4*)(bp + (long)j * K_DIM + t * 16) = o;
    if (t == 0) { dsp[j] = deq[src]; qbp[j] = qb[src]; }
}

// ---------------------------------------------------------------------------
// Kernel 3: int8 GEMM, C[m, j] = (sum_k xq[m,k]*Bp[j,k] + qbp[j]) * dsp[j]
// 128x128 tile, BK=128, 4 waves (2x2), each wave 64x64 = 4x4 of 16x16 tiles.
// mfma_i32_16x16x64_i8. global_load_lds w=16, linear LDS dest with
// inverse-swizzled global source; ds_read_b128 with slot^(row&7) swizzle.
// ---------------------------------------------------------------------------
__device__ __forceinline__ void gload_lds16(const void* g, void* l)
{
    __builtin_amdgcn_global_load_lds(
        (const __attribute__((address_space(1))) uint32_t*)g,
        (__attribute__((address_space(3))) uint32_t*)l, 16, 0, 0);
}

__global__ __launch_bounds__(256) void gemm_i8_kernel(
    const int8_t* __restrict__ A, const int8_t* __restrict__ B,
    const float* __restrict__ dsp, const int* __restrict__ qbp,
    float* __restrict__ C)
{
    __shared__ int8_t As[BM * BK];
    __shared__ int8_t Bs[BN * BK];

    // XCD-aware swizzle (grid = 2048, divisible by 8)
    int bid = blockIdx.x;
    int cpx = gridDim.x >> 3;
    int swz = (bid & 7) * cpx + (bid >> 3);
    int bn = swz % (N_DIM / BN);
    int bm = swz / (N_DIM / BN);
    int brow = bm * BM, bcol = bn * BN;

    int t = threadIdx.x;
    int l = t & 63;
    int wv = t >> 6;
    int wr = (wv >> 1) * 64;   // wave row offset in tile
    int wc = (wv & 1) * 64;    // wave col offset in tile

    // Staging source addresses. Physical LDS chunk cid = i*256+t at byte cid*16.
    // row = cid>>3, physical slot p = cid&7 holds logical slot p^(row&7).
    const int8_t* ga[4];
    const int8_t* gb[4];
#pragma unroll
    for (int i = 0; i < 4; ++i) {
        int cid = i * 256 + t;
        int row = cid >> 3;
        int p = cid & 7;
        int lg = p ^ (row & 7);
        ga[i] = A + (long)(brow + row) * K_DIM + lg * 16;
        gb[i] = B + (long)(bcol + row) * K_DIM + lg * 16;
    }

    i32x4 acc[4][4] = {};

    for (int kt = 0; kt < K_DIM / BK; ++kt) {
#pragma unroll
        for (int i = 0; i < 4; ++i) {
            gload_lds16(ga[i], As + (i * 256 + t) * 16);
            ga[i] += BK;
        }
#pragma unroll
        for (int i = 0; i < 4; ++i) {
            gload_lds16(gb[i], Bs + (i * 256 + t) * 16);
            gb[i] += BK;
        }
        __syncthreads();

#pragma unroll
        for (int kk = 0; kk < 2; ++kk) {
            i32x4 af[4], bf[4];
#pragma unroll
            for (int m = 0; m < 4; ++m) {
                int row = wr + m * 16 + (l & 15);
                int slot = (kk * 4 + (l >> 4)) ^ (row & 7);
                af[m] = *(const i32x4*)(As + row * BK + slot * 16);
            }
#pragma unroll
            for (int n = 0; n < 4; ++n) {
                int row = wc + n * 16 + (l & 15);
                int slot = (kk * 4 + (l >> 4)) ^ (row & 7);
                bf[n] = *(const i32x4*)(Bs + row * BK + slot * 16);
            }
#pragma unroll
            for (int m = 0; m < 4; ++m)
#pragma unroll
                for (int n = 0; n < 4; ++n)
                    acc[m][n] = __builtin_amdgcn_mfma_i32_16x16x64_i8(
                        af[m], bf[n], acc[m][n], 0, 0, 0);
        }
        __syncthreads();
    }

    // Epilogue: C/D layout col = lane&15, row = (lane>>4)*4 + reg
#pragma unroll
    for (int n = 0; n < 4; ++n) {
        int gc = bcol + wc + n * 16 + (l & 15);
        float ds = dsp[gc];
        int qb = qbp[gc];
#pragma unroll
        for (int m = 0; m < 4; ++m) {
            int gr0 = brow + wr + m * 16 + ((l >> 4) * 4);
#pragma unroll
            for (int r = 0; r < 4; ++r) {
                float val = (float)(acc[m][n][r] + qb) * ds;
                C[(long)(gr0 + r) * N_DIM + gc] = val;
            }
        }
    }
}

// ---------------------------------------------------------------------------
extern "C" void kernel_launch(void* const* d_in, const int* in_sizes, int n_in,
                              void* d_out, int out_size, void* d_ws, size_t ws_size,
                              hipStream_t stream)
{
    (void)in_sizes; (void)n_in; (void)out_size; (void)ws_size;
    const float* x   = (const float*)d_in[0];
    const int*   w   = (const int*)d_in[1];
    const float* is  = (const float*)d_in[2];
    const int*   io  = (const int*)d_in[3];
    const float* dq  = (const float*)d_in[4];
    const int*   qb  = (const int*)d_in[5];
    const int*   idx = (const int*)d_in[6];
    float* out = (float*)d_out;

    int8_t* xq  = (int8_t*)d_ws;                           // 33554432 B
    int8_t* bp  = xq + (size_t)M_DIM * K_DIM;              // 16777216 B
    float*  dsp = (float*)(bp + (size_t)N_DIM * K_DIM);    // 16384 B
    int*    qbp = (int*)(dsp + N_DIM);                     // 16384 B

    long quant_blocks = ((long)M_DIM * K_DIM) / 16 / 256;  // 8192
    quant_x_kernel<<<(int)quant_blocks, 256, 0, stream>>>(x, is, io, xq);
    pack_w_kernel<<<N_DIM, 256, 0, stream>>>(w, idx, dq, qb, bp, dsp, qbp);
    gemm_i8_kernel<<<(M_DIM / BM) * (N_DIM / BN), 256, 0, stream>>>(xq, bp, dsp, qbp, out);
}

// Round 2
// 201.648 us; speedup vs baseline: 1.0410x; 1.0410x over previous
//
#include <hip/hip_runtime.h>
#include <hip/hip_bf16.h>
#include <stdint.h>

#define M_DIM 8192
#define K_DIM 4096
#define N_DIM 4096

#define BM 256
#define BN 256
#define BKB 64              // K-bytes (=i8 elems) per tile
#define NT (K_DIM / BKB)    // 64 K-tiles
#define ATILE (BM * BKB)    // 16384 B
#define BTILE (BN * BKB)    // 16384 B

typedef int i32x4 __attribute__((ext_vector_type(4)));

// ---------------------------------------------------------------------------
// Kernel 1: per-tensor activation quantization f32 -> i8 (unchanged, passing)
// ---------------------------------------------------------------------------
__global__ __launch_bounds__(256) void quant_x_kernel(
    const float* __restrict__ x, const float* __restrict__ scale_p,
    const int* __restrict__ off_p, int8_t* __restrict__ xq)
{
    const float s = scale_p[0];
    const float off = (float)off_p[0];
    long base = ((long)blockIdx.x * 256 + threadIdx.x) * 16;
    const float4* xin = (const float4*)(x + base);
    float v[16];
    *(float4*)(v + 0)  = xin[0];
    *(float4*)(v + 4)  = xin[1];
    *(float4*)(v + 8)  = xin[2];
    *(float4*)(v + 12) = xin[3];
    uint32_t pk[4];
#pragma unroll
    for (int g = 0; g < 4; ++g) {
        uint32_t p = 0;
#pragma unroll
        for (int j = 0; j < 4; ++j) {
            float q = rintf(v[g * 4 + j] / s) + off;
            q = fminf(fmaxf(q, -128.0f), 127.0f);
            int qi = (int)q;
            p |= ((uint32_t)(qi & 0xff)) << (8 * j);
        }
        pk[g] = p;
    }
    uint4 o; o.x = pk[0]; o.y = pk[1]; o.z = pk[2]; o.w = pk[3];
    *(uint4*)(xq + base) = o;
}

// ---------------------------------------------------------------------------
// Kernel 2: weight pack + permutation fold (unchanged, passing)
// ---------------------------------------------------------------------------
__global__ __launch_bounds__(256) void pack_w_kernel(
    const int* __restrict__ w, const int* __restrict__ index,
    const float* __restrict__ deq, const int* __restrict__ qb,
    int8_t* __restrict__ bp, float* __restrict__ dsp, int* __restrict__ qbp)
{
    int j = blockIdx.x;
    int t = threadIdx.x;
    int src = index[j];
    const int4* wrow = (const int4*)(w + (long)src * K_DIM);
    uint32_t pk[4];
#pragma unroll
    for (int g = 0; g < 4; ++g) {
        int4 c = wrow[t * 4 + g];
        pk[g] = ((uint32_t)(c.x & 0xff)) | (((uint32_t)(c.y & 0xff)) << 8) |
                (((uint32_t)(c.z & 0xff)) << 16) | (((uint32_t)(c.w & 0xff)) << 24);
    }
    uint4 o; o.x = pk[0]; o.y = pk[1]; o.z = pk[2]; o.w = pk[3];
    *(uint4*)(bp + (long)j * K_DIM + t * 16) = o;
    if (t == 0) { dsp[j] = deq[src]; qbp[j] = qb[src]; }
}

// ---------------------------------------------------------------------------
// Kernel 3: 256x256 deep-pipelined int8 GEMM (T2+T3+T4+T5).
// 8 waves (2M x 4N), wave tile 128x64, ring-of-3 LDS K-tile buffers (96KB),
// 2 phases per K-tile: {ds_read frags || global_load_lds prefetch of tile
// t+2 -> s_barrier -> lgkmcnt(0) -> setprio(1) 16 MFMA setprio(0)}.
// Counted vmcnt(4) at tile boundary only (tile t+2's 4 loads stay in flight).
// LDS swizzle: chunk (row, s) stored at phys slot s ^ ((row>>1)&3) -> uniform
// 8 lanes/bank-quad per ds_read_b128 (= b128 minimum, conflict-free).
// ---------------------------------------------------------------------------
__device__ __forceinline__ void gload_lds16(const int8_t* g, int8_t* l)
{
    __builtin_amdgcn_global_load_lds(
        (const __attribute__((address_space(1))) uint32_t*)g,
        (__attribute__((address_space(3))) uint32_t*)l, 16, 0, 0);
}

__global__ __launch_bounds__(512, 2) void gemm_i8_kernel(
    const int8_t* __restrict__ A, const int8_t* __restrict__ B,
    const float* __restrict__ dsp, const int* __restrict__ qbp,
    float* __restrict__ C)
{
    __shared__ int8_t lds[3][ATILE + BTILE];   // 3 x 32KB = 96KB

    // XCD-aware bijective swizzle (grid = 512, divisible by 8).
    // bn-major chunks: each XCD keeps 2 B-panels (2MB) hot in its L2.
    int bid = blockIdx.x;
    int swz = (bid & 7) * (gridDim.x >> 3) + (bid >> 3);
    int bm = swz & 31;              // M/BM = 32
    int bn = swz >> 5;              // N/BN = 16
    int brow = bm * BM, bcol = bn * BN;

    int t = threadIdx.x;
    int wv = t >> 6;
    int l  = t & 63;
    int lr = l & 15;                // row within 16x16 fragment
    int ls = l >> 4;                // logical 16B k-slot
    int wrM = (wv >> 2) * 128;      // wave row offset (2 M-waves)
    int wcN = (wv & 3) * 64;        // wave col offset (4 N-waves)
    int pslot = ls ^ ((lr >> 1) & 3);   // swizzled physical slot (lane-const)

    // ds_read byte offsets within a K-tile buffer
    int aoff[8], boff[4];
#pragma unroll
    for (int m = 0; m < 8; ++m)
        aoff[m] = (wrM + m * 16 + lr) * BKB + pslot * 16;
#pragma unroll
    for (int n = 0; n < 4; ++n)
        boff[n] = ATILE + (wcN + n * 16 + lr) * BKB + pslot * 16;

    // Staging: per thread 2 A-chunks + 2 B-chunks (16B each) per K-tile.
    // Physical chunk ca at LDS offset ca*16 (linear, wave-uniform base +
    // lane*16); global source pre-swizzled: logical slot = (ca&3)^((row>>1)&3)
    const int8_t* sa[2]; int da[2];
    const int8_t* sb[2]; int db[2];
#pragma unroll
    for (int i = 0; i < 2; ++i) {
        int ca = i * 512 + t;
        int row = ca >> 2;
        int lg = (ca & 3) ^ ((row >> 1) & 3);
        sa[i] = A + (long)(brow + row) * K_DIM + lg * 16;
        da[i] = ca * 16;
        sb[i] = B + (long)(bcol + row) * K_DIM + lg * 16;
        db[i] = ATILE + ca * 16;
    }

    // Prologue: stage K-tiles 0 and 1 (issue order per thread: A,A,B,B each)
#pragma unroll
    for (int p = 0; p < 2; ++p) {
        gload_lds16(sa[0], &lds[p][da[0]]);
        gload_lds16(sa[1], &lds[p][da[1]]);
        gload_lds16(sb[0], &lds[p][db[0]]);
        gload_lds16(sb[1], &lds[p][db[1]]);
        sa[0] += BKB; sa[1] += BKB; sb[0] += BKB; sb[1] += BKB;
    }
    asm volatile("s_waitcnt vmcnt(4)" ::: "memory");   // tile 0 resident
    __builtin_amdgcn_s_barrier();

    i32x4 acc[8][4] = {};

    for (int kt = 0; kt < NT; ++kt) {
        const int cur = kt % 3;
        const int stg = (kt + 2) % 3;
        const bool do_stage = (kt + 2) < NT;
        const int8_t* base = lds[cur];

        i32x4 af[4], bf[4];

        // ---------- phase 0: B frags + A frags m=0..3, stage A of t+2 ----
#pragma unroll
        for (int n = 0; n < 4; ++n) bf[n] = *(const i32x4*)(base + boff[n]);
#pragma unroll
        for (int m = 0; m < 4; ++m) af[m] = *(const i32x4*)(base + aoff[m]);
        if (do_stage) {
            gload_lds16(sa[0], &lds[stg][da[0]]);
            gload_lds16(sa[1], &lds[stg][da[1]]);
            sa[0] += BKB; sa[1] += BKB;
        }
        __builtin_amdgcn_s_barrier();
        asm volatile("s_waitcnt lgkmcnt(0)" ::: "memory");
        __builtin_amdgcn_sched_barrier(0);
        __builtin_amdgcn_s_setprio(1);
#pragma unroll
        for (int m = 0; m < 4; ++m)
#pragma unroll
            for (int n = 0; n < 4; ++n)
                acc[m][n] = __builtin_amdgcn_mfma_i32_16x16x64_i8(
                    af[m], bf[n], acc[m][n], 0, 0, 0);
        __builtin_amdgcn_s_setprio(0);
        __builtin_amdgcn_s_barrier();

        // ---------- phase 1: A frags m=4..7 (reuse bf), stage B of t+2 ----
#pragma unroll
        for (int m = 0; m < 4; ++m) af[m] = *(const i32x4*)(base + aoff[m + 4]);
        if (do_stage) {
            gload_lds16(sb[0], &lds[stg][db[0]]);
            gload_lds16(sb[1], &lds[stg][db[1]]);
            sb[0] += BKB; sb[1] += BKB;
        }
        __builtin_amdgcn_s_barrier();
        asm volatile("s_waitcnt lgkmcnt(0)" ::: "memory");
        __builtin_amdgcn_sched_barrier(0);
        __builtin_amdgcn_s_setprio(1);
#pragma unroll
        for (int m = 0; m < 4; ++m)
#pragma unroll
            for (int n = 0; n < 4; ++n)
                acc[m + 4][n] = __builtin_amdgcn_mfma_i32_16x16x64_i8(
                    af[m], bf[n], acc[m + 4][n], 0, 0, 0);
        __builtin_amdgcn_s_setprio(0);
        // Tile boundary: counted vmcnt — tile t+2's 4 loads stay in flight,
        // everything older (tile t+1) guaranteed resident after the barrier.
        if (do_stage) asm volatile("s_waitcnt vmcnt(4)" ::: "memory");
        else          asm volatile("s_waitcnt vmcnt(0)" ::: "memory");
        __builtin_amdgcn_s_barrier();
    }

    // Epilogue: C/D layout col = lane&15, row = (lane>>4)*4 + reg
#pragma unroll
    for (int n = 0; n < 4; ++n) {
        int gc = bcol + wcN + n * 16 + lr;
        float ds = dsp[gc];
        int qb = qbp[gc];
#pragma unroll
        for (int m = 0; m < 8; ++m) {
            int gr0 = brow + wrM + m * 16 + ls * 4;
#pragma unroll
            for (int r = 0; r < 4; ++r) {
                C[(long)(gr0 + r) * N_DIM + gc] = (float)(acc[m][n][r] + qb) * ds;
            }
        }
    }
}

// ---------------------------------------------------------------------------
extern "C" void kernel_launch(void* const* d_in, const int* in_sizes, int n_in,
                              void* d_out, int out_size, void* d_ws, size_t ws_size,
                              hipStream_t stream)
{
    (void)in_sizes; (void)n_in; (void)out_size; (void)ws_size;
    const float* x   = (const float*)d_in[0];
    const int*   w   = (const int*)d_in[1];
    const float* is  = (const float*)d_in[2];
    const int*   io  = (const int*)d_in[3];
    const float* dq  = (const float*)d_in[4];
    const int*   qb  = (const int*)d_in[5];
    const int*   idx = (const int*)d_in[6];
    float* out = (float*)d_out;

    int8_t* xq  = (int8_t*)d_ws;                           // 33554432 B
    int8_t* bp  = xq + (size_t)M_DIM * K_DIM;              // 16777216 B
    float*  dsp = (float*)(bp + (size_t)N_DIM * K_DIM);    // 16384 B
    int*    qbp = (int*)(dsp + N_DIM);                     // 16384 B

    long quant_blocks = ((long)M_DIM * K_DIM) / 16 / 256;  // 8192
    quant_x_kernel<<<(int)quant_blocks, 256, 0, stream>>>(x, is, io, xq);
    pack_w_kernel<<<N_DIM, 256, 0, stream>>>(w, idx, dq, qb, bp, dsp, qbp);
    gemm_i8_kernel<<<(M_DIM / BM) * (N_DIM / BN), 512, 0, stream>>>(xq, bp, dsp, qbp, out);
}

// Round 3
// 197.191 us; speedup vs baseline: 1.0645x; 1.0226x over previous
//
#include <hip/hip_runtime.h>
#include <hip/hip_bf16.h>
#include <stdint.h>

#define M_DIM 8192
#define K_DIM 4096
#define N_DIM 4096

#define BM 256
#define BN 256
#define BKB 64              // K-bytes (=i8 elems) per tile
#define NT (K_DIM / BKB)    // 64 K-tiles
#define ATILE (BM * BKB)    // 16384 B
#define BTILE (BN * BKB)    // 16384 B

typedef int i32x4 __attribute__((ext_vector_type(4)));

// ---------------------------------------------------------------------------
// Kernel 1: per-tensor activation quantization f32 -> i8 (unchanged, passing)
// ---------------------------------------------------------------------------
__global__ __launch_bounds__(256) void quant_x_kernel(
    const float* __restrict__ x, const float* __restrict__ scale_p,
    const int* __restrict__ off_p, int8_t* __restrict__ xq)
{
    const float s = scale_p[0];
    const float off = (float)off_p[0];
    long base = ((long)blockIdx.x * 256 + threadIdx.x) * 16;
    const float4* xin = (const float4*)(x + base);
    float v[16];
    *(float4*)(v + 0)  = xin[0];
    *(float4*)(v + 4)  = xin[1];
    *(float4*)(v + 8)  = xin[2];
    *(float4*)(v + 12) = xin[3];
    uint32_t pk[4];
#pragma unroll
    for (int g = 0; g < 4; ++g) {
        uint32_t p = 0;
#pragma unroll
        for (int j = 0; j < 4; ++j) {
            float q = rintf(v[g * 4 + j] / s) + off;
            q = fminf(fmaxf(q, -128.0f), 127.0f);
            int qi = (int)q;
            p |= ((uint32_t)(qi & 0xff)) << (8 * j);
        }
        pk[g] = p;
    }
    uint4 o; o.x = pk[0]; o.y = pk[1]; o.z = pk[2]; o.w = pk[3];
    *(uint4*)(xq + base) = o;
}

// ---------------------------------------------------------------------------
// Kernel 2: weight pack + permutation fold (unchanged, passing)
// ---------------------------------------------------------------------------
__global__ __launch_bounds__(256) void pack_w_kernel(
    const int* __restrict__ w, const int* __restrict__ index,
    const float* __restrict__ deq, const int* __restrict__ qb,
    int8_t* __restrict__ bp, float* __restrict__ dsp, int* __restrict__ qbp)
{
    int j = blockIdx.x;
    int t = threadIdx.x;
    int src = index[j];
    const int4* wrow = (const int4*)(w + (long)src * K_DIM);
    uint32_t pk[4];
#pragma unroll
    for (int g = 0; g < 4; ++g) {
        int4 c = wrow[t * 4 + g];
        pk[g] = ((uint32_t)(c.x & 0xff)) | (((uint32_t)(c.y & 0xff)) << 8) |
                (((uint32_t)(c.z & 0xff)) << 16) | (((uint32_t)(c.w & 0xff)) << 24);
    }
    uint4 o; o.x = pk[0]; o.y = pk[1]; o.z = pk[2]; o.w = pk[3];
    *(uint4*)(bp + (long)j * K_DIM + t * 16) = o;
    if (t == 0) { dsp[j] = deq[src]; qbp[j] = qb[src]; }
}

// ---------------------------------------------------------------------------
// Kernel 3: 256x256 int8 GEMM, single-barrier-per-K-tile wave-slip schedule.
// 8 waves (2M x 4N), wave tile 128x64, ring-of-3 LDS K-tile buffers (96KB).
// Per K-tile: {12 ds_read_b128 || 4 global_load_lds of tile t+2} ->
// lgkmcnt(0) -> setprio(1) 32 MFMA setprio(0) -> vmcnt(4) -> s_barrier.
// Correctness: lgkmcnt(0) before tile-end barrier ensures no wave reads
// buffer t-1 after the barrier, so staging into buffer (t+2)%3 == (t-1)%3
// during tile t+1 is safe. vmcnt(4)+barrier ensures tile t+1 resident for
// all waves (vmcnt retires in order; only t+2's 4 loads may remain).
// ---------------------------------------------------------------------------
__device__ __forceinline__ void gload_lds16(const int8_t* g, int8_t* l)
{
    __builtin_amdgcn_global_load_lds(
        (const __attribute__((address_space(1))) uint32_t*)g,
        (__attribute__((address_space(3))) uint32_t*)l, 16, 0, 0);
}

__global__ __launch_bounds__(512, 2) void gemm_i8_kernel(
    const int8_t* __restrict__ A, const int8_t* __restrict__ B,
    const float* __restrict__ dsp, const int* __restrict__ qbp,
    float* __restrict__ C)
{
    __shared__ int8_t lds[3][ATILE + BTILE];   // 3 x 32KB = 96KB

    // XCD-aware bijective swizzle (grid = 512, divisible by 8)
    int bid = blockIdx.x;
    int swz = (bid & 7) * (gridDim.x >> 3) + (bid >> 3);
    int bm = swz & 31;              // M/BM = 32
    int bn = swz >> 5;              // N/BN = 16
    int brow = bm * BM, bcol = bn * BN;

    int t = threadIdx.x;
    int wv = t >> 6;
    int l  = t & 63;
    int lr = l & 15;                // row within 16x16 fragment
    int ls = l >> 4;                // logical 16B k-slot
    int wrM = (wv >> 2) * 128;      // wave row offset (2 M-waves)
    int wcN = (wv & 3) * 64;        // wave col offset (4 N-waves)
    int pslot = ls ^ ((lr >> 1) & 3);   // swizzled physical slot (lane-const)

    // ds_read byte offsets within a K-tile buffer
    int aoff[8], boff[4];
#pragma unroll
    for (int m = 0; m < 8; ++m)
        aoff[m] = (wrM + m * 16 + lr) * BKB + pslot * 16;
#pragma unroll
    for (int n = 0; n < 4; ++n)
        boff[n] = ATILE + (wcN + n * 16 + lr) * BKB + pslot * 16;

    // Staging: per thread 2 A-chunks + 2 B-chunks (16B each) per K-tile.
    // Linear LDS dest (chunk ca at byte ca*16); global source pre-swizzled:
    // logical slot = (ca&3) ^ ((row>>1)&3).
    const int8_t* sa[2]; int da[2];
    const int8_t* sb[2]; int db[2];
#pragma unroll
    for (int i = 0; i < 2; ++i) {
        int ca = i * 512 + t;
        int row = ca >> 2;
        int lg = (ca & 3) ^ ((row >> 1) & 3);
        sa[i] = A + (long)(brow + row) * K_DIM + lg * 16;
        da[i] = ca * 16;
        sb[i] = B + (long)(bcol + row) * K_DIM + lg * 16;
        db[i] = ATILE + ca * 16;
    }

    // Prologue: stage K-tiles 0 and 1
#pragma unroll
    for (int p = 0; p < 2; ++p) {
        gload_lds16(sa[0], &lds[p][da[0]]);
        gload_lds16(sa[1], &lds[p][da[1]]);
        gload_lds16(sb[0], &lds[p][db[0]]);
        gload_lds16(sb[1], &lds[p][db[1]]);
        sa[0] += BKB; sa[1] += BKB; sb[0] += BKB; sb[1] += BKB;
    }
    asm volatile("s_waitcnt vmcnt(4)" ::: "memory");   // tile 0 resident
    __builtin_amdgcn_s_barrier();

    i32x4 acc[8][4] = {};
    int cur = 0, stg = 2;

    for (int kt = 0; kt < NT; ++kt) {
        const bool do_stage = (kt + 2) < NT;
        const int8_t* base = lds[cur];

        i32x4 af[8], bf[4];
        // Issue all fragment reads for this tile (DS pipe), then the
        // prefetch loads for tile t+2 (VMEM pipe) — long-latency ops early.
#pragma unroll
        for (int n = 0; n < 4; ++n) bf[n] = *(const i32x4*)(base + boff[n]);
#pragma unroll
        for (int m = 0; m < 8; ++m) af[m] = *(const i32x4*)(base + aoff[m]);
        if (do_stage) {
            int8_t* sdst = lds[stg];
            gload_lds16(sa[0], sdst + da[0]);
            gload_lds16(sa[1], sdst + da[1]);
            gload_lds16(sb[0], sdst + db[0]);
            gload_lds16(sb[1], sdst + db[1]);
            sa[0] += BKB; sa[1] += BKB; sb[0] += BKB; sb[1] += BKB;
        }
        asm volatile("s_waitcnt lgkmcnt(0)" ::: "memory");
        __builtin_amdgcn_sched_barrier(0);
        __builtin_amdgcn_s_setprio(1);
#pragma unroll
        for (int m = 0; m < 8; ++m)
#pragma unroll
            for (int n = 0; n < 4; ++n)
                acc[m][n] = __builtin_amdgcn_mfma_i32_16x16x64_i8(
                    af[m], bf[n], acc[m][n], 0, 0, 0);
        __builtin_amdgcn_s_setprio(0);
        __builtin_amdgcn_sched_barrier(0);
        // Tile boundary: counted vmcnt — only tile t+2's 4 loads may remain
        // in flight; tile t+1 is resident for every wave after the barrier.
        if (do_stage) asm volatile("s_waitcnt vmcnt(4)" ::: "memory");
        else          asm volatile("s_waitcnt vmcnt(0)" ::: "memory");
        __builtin_amdgcn_s_barrier();
        cur = (cur == 2) ? 0 : cur + 1;
        stg = (stg == 2) ? 0 : stg + 1;
    }

    // Epilogue: C/D layout col = lane&15, row = (lane>>4)*4 + reg
#pragma unroll
    for (int n = 0; n < 4; ++n) {
        int gc = bcol + wcN + n * 16 + lr;
        float ds = dsp[gc];
        int qb = qbp[gc];
#pragma unroll
        for (int m = 0; m < 8; ++m) {
            int gr0 = brow + wrM + m * 16 + ls * 4;
#pragma unroll
            for (int r = 0; r < 4; ++r) {
                C[(long)(gr0 + r) * N_DIM + gc] = (float)(acc[m][n][r] + qb) * ds;
            }
        }
    }
}

// ---------------------------------------------------------------------------
extern "C" void kernel_launch(void* const* d_in, const int* in_sizes, int n_in,
                              void* d_out, int out_size, void* d_ws, size_t ws_size,
                              hipStream_t stream)
{
    (void)in_sizes; (void)n_in; (void)out_size; (void)ws_size;
    const float* x   = (const float*)d_in[0];
    const int*   w   = (const int*)d_in[1];
    const float* is  = (const float*)d_in[2];
    const int*   io  = (const int*)d_in[3];
    const float* dq  = (const float*)d_in[4];
    const int*   qb  = (const int*)d_in[5];
    const int*   idx = (const int*)d_in[6];
    float* out = (float*)d_out;

    int8_t* xq  = (int8_t*)d_ws;                           // 33554432 B
    int8_t* bp  = xq + (size_t)M_DIM * K_DIM;              // 16777216 B
    float*  dsp = (float*)(bp + (size_t)N_DIM * K_DIM);    // 16384 B
    int*    qbp = (int*)(dsp + N_DIM);                     // 16384 B

    long quant_blocks = ((long)M_DIM * K_DIM) / 16 / 256;  // 8192
    quant_x_kernel<<<(int)quant_blocks, 256, 0, stream>>>(x, is, io, xq);
    pack_w_kernel<<<N_DIM, 256, 0, stream>>>(w, idx, dq, qb, bp, dsp, qbp);
    gemm_i8_kernel<<<(M_DIM / BM) * (N_DIM / BN), 512, 0, stream>>>(xq, bp, dsp, qbp, out);
}